// Round 1
// baseline (662.522 us; speedup 1.0000x reference)
//
#include <hip/hip_runtime.h>

// Problem constants (B=2, S=2048, D_IN=2048, H=16, G=4, HD=128)
#define S_LEN 2048
#define NROWS 4096      // B*S
#define DIN   2048
#define DQG   4096      // 2*D_OUT
#define DKV   1024      // G*HD (K) + G*HD (V)

typedef __bf16 bf16x8 __attribute__((ext_vector_type(8)));
typedef float  floatx4 __attribute__((ext_vector_type(4)));
typedef unsigned short u16;

__device__ __forceinline__ u16 f2bf(float f) {
  unsigned int u = __float_as_uint(f);
  u += 0x7fffu + ((u >> 16) & 1u);   // RNE
  return (u16)(u >> 16);
}

__device__ __forceinline__ void gload_lds16(const void* g, void* l) {
  __builtin_amdgcn_global_load_lds(
      (__attribute__((address_space(1))) void*)(void*)(g),
      (__attribute__((address_space(3))) void*)(l), 16, 0, 0);
}

// ---------------- elementwise fp32 -> bf16 ----------------
__global__ __launch_bounds__(256) void cvt_f32_bf16(const float* __restrict__ src,
                                                    u16* __restrict__ dst, int n4) {
  int i = blockIdx.x * 256 + threadIdx.x;
  if (i >= n4) return;
  float4 v = reinterpret_cast<const float4*>(src)[i];
  ushort4 o;
  o.x = f2bf(v.x); o.y = f2bf(v.y); o.z = f2bf(v.z); o.w = f2bf(v.w);
  reinterpret_cast<ushort4*>(dst)[i] = o;
}

// ---------------- transpose + convert: src[R][C] f32 -> dst[C][R] bf16 ----------------
__global__ __launch_bounds__(256) void tcvt(const float* __restrict__ src,
                                            u16* __restrict__ dst,
                                            int R, int C, int dld) {
  __shared__ float tile[32][33];
  const int c0 = blockIdx.x * 32, r0 = blockIdx.y * 32;
  const int t = threadIdx.x;
  {
    const int rl = t >> 3, cl4 = (t & 7) * 4;
    const float4 v = *reinterpret_cast<const float4*>(src + (size_t)(r0 + rl) * C + c0 + cl4);
    tile[rl][cl4 + 0] = v.x; tile[rl][cl4 + 1] = v.y;
    tile[rl][cl4 + 2] = v.z; tile[rl][cl4 + 3] = v.w;
  }
  __syncthreads();
  {
    const int cl = t >> 3, rl4 = (t & 7) * 4;
    ushort4 o;
    o.x = f2bf(tile[rl4 + 0][cl]); o.y = f2bf(tile[rl4 + 1][cl]);
    o.z = f2bf(tile[rl4 + 2][cl]); o.w = f2bf(tile[rl4 + 3][cl]);
    *reinterpret_cast<ushort4*>(dst + (size_t)(c0 + cl) * dld + r0 + rl4) = o;
  }
}

// ---------------- m97-style bf16 GEMM: C[M][N] = A[M][K] @ Bt[N][K]^T ----------------
__global__ __launch_bounds__(256) void gemm_bt(const u16* __restrict__ A,
                                               const u16* __restrict__ Bt,
                                               float* __restrict__ C,
                                               int M, int N, int K) {
  __shared__ __align__(16) u16 As[128 * 32];
  __shared__ __align__(16) u16 Bs[128 * 32];
  const int tid = threadIdx.x, wv = tid >> 6, lane = tid & 63;
  const int m0 = blockIdx.y * 128, n0 = blockIdx.x * 128;
  const int wm = (wv >> 1) * 64, wn = (wv & 1) * 64;
  const int frow = lane & 15, fk = (lane >> 4) * 8;
  const int srow = lane >> 2, skoff = (lane & 3) * 8;
  floatx4 acc[4][4] = {};
  for (int k0 = 0; k0 < K; k0 += 32) {
#pragma unroll
    for (int i = 0; i < 2; ++i) {
      const int rr = (wv * 2 + i) * 16;
      gload_lds16(A  + (size_t)(m0 + rr + srow) * K + k0 + skoff, &As[rr * 32]);
      gload_lds16(Bt + (size_t)(n0 + rr + srow) * K + k0 + skoff, &Bs[rr * 32]);
    }
    __syncthreads();
    bf16x8 af[4], bfr[4];
#pragma unroll
    for (int mi = 0; mi < 4; ++mi)
      af[mi] = *reinterpret_cast<const bf16x8*>(&As[(wm + mi * 16 + frow) * 32 + fk]);
#pragma unroll
    for (int ni = 0; ni < 4; ++ni)
      bfr[ni] = *reinterpret_cast<const bf16x8*>(&Bs[(wn + ni * 16 + frow) * 32 + fk]);
#pragma unroll
    for (int mi = 0; mi < 4; ++mi)
#pragma unroll
      for (int ni = 0; ni < 4; ++ni)
        acc[mi][ni] = __builtin_amdgcn_mfma_f32_16x16x32_bf16(af[mi], bfr[ni], acc[mi][ni], 0, 0, 0);
    __syncthreads();
  }
  const int crow = (lane >> 4) * 4, ccol = lane & 15;
#pragma unroll
  for (int mi = 0; mi < 4; ++mi)
#pragma unroll
    for (int ni = 0; ni < 4; ++ni) {
      float* cp = C + (size_t)(m0 + wm + mi * 16 + crow) * N + (n0 + wn + ni * 16 + ccol);
#pragma unroll
      for (int r = 0; r < 4; ++r) cp[(size_t)r * N] = acc[mi][ni][r];
    }
}

// ---------------- fused RMSNorm + RoPE for Q (from QG fp32) ----------------
// one wave per (row, head): lane holds elems d=lane and d=lane+64 (the rotate-half pair)
__global__ __launch_bounds__(256) void qnorm_rope(const float* __restrict__ QG,
                                                  const float* __restrict__ w,
                                                  const float* __restrict__ cosT,
                                                  const float* __restrict__ sinT,
                                                  u16* __restrict__ Qb) {
  const int wv = threadIdx.x >> 6, lane = threadIdx.x & 63;
  const int idx = blockIdx.x * 4 + wv;      // row*16 + h
  const int h = idx & 15, row = idx >> 4;   // row = b*S + s
  const int s = row & (S_LEN - 1), b = row >> 11;
  const float* base = QG + (size_t)row * DQG + h * 256;
  const float v0 = base[lane], v1 = base[lane + 64];
  float ss = v0 * v0 + v1 * v1;
#pragma unroll
  for (int m = 32; m >= 1; m >>= 1) ss += __shfl_xor(ss, m);
  const float rn = rsqrtf(ss * (1.0f / 128.0f) + 1e-6f);
  const float n0 = v0 * rn * (1.0f + w[lane]);
  const float n1 = v1 * rn * (1.0f + w[lane + 64]);
  const float c0 = cosT[(size_t)s * 128 + lane], c1 = cosT[(size_t)s * 128 + lane + 64];
  const float sn0 = sinT[(size_t)s * 128 + lane], sn1 = sinT[(size_t)s * 128 + lane + 64];
  u16* qb = Qb + ((size_t)(b * 16 + h) * S_LEN + s) * 128;
  qb[lane]      = f2bf(n0 * c0 - n1 * sn0);
  qb[lane + 64] = f2bf(n1 * c1 + n0 * sn1);
}

// ---------------- fused RMSNorm + RoPE for K (from KV fp32, cols 0..511) ----------------
__global__ __launch_bounds__(256) void knorm_rope(const float* __restrict__ KV,
                                                  const float* __restrict__ w,
                                                  const float* __restrict__ cosT,
                                                  const float* __restrict__ sinT,
                                                  u16* __restrict__ Kb) {
  const int wv = threadIdx.x >> 6, lane = threadIdx.x & 63;
  const int idx = blockIdx.x * 4 + wv;      // row*4 + g
  const int g = idx & 3, row = idx >> 2;
  const int s = row & (S_LEN - 1), b = row >> 11;
  const float* base = KV + (size_t)row * DKV + g * 128;
  const float v0 = base[lane], v1 = base[lane + 64];
  float ss = v0 * v0 + v1 * v1;
#pragma unroll
  for (int m = 32; m >= 1; m >>= 1) ss += __shfl_xor(ss, m);
  const float rn = rsqrtf(ss * (1.0f / 128.0f) + 1e-6f);
  const float n0 = v0 * rn * (1.0f + w[lane]);
  const float n1 = v1 * rn * (1.0f + w[lane + 64]);
  const float c0 = cosT[(size_t)s * 128 + lane], c1 = cosT[(size_t)s * 128 + lane + 64];
  const float sn0 = sinT[(size_t)s * 128 + lane], sn1 = sinT[(size_t)s * 128 + lane + 64];
  u16* kb = Kb + ((size_t)(b * 4 + g) * S_LEN + s) * 128;
  kb[lane]      = f2bf(n0 * c0 - n1 * sn0);
  kb[lane + 64] = f2bf(n1 * c1 + n0 * sn1);
}

// ---------------- V: KV fp32 cols 512..1023 -> Vt bf16 [b][g][d][s] ----------------
__global__ __launch_bounds__(256) void vtrans(const float* __restrict__ KV,
                                              u16* __restrict__ Vt) {
  __shared__ float tile[32][33];
  const int bg = blockIdx.z;                 // b*4+g
  const int s0 = blockIdx.x * 32, d0 = blockIdx.y * 32;
  const int b = bg >> 2, g = bg & 3;
  const int t = threadIdx.x;
  {
    const int sl = t >> 3, dl4 = (t & 7) * 4;
    const float4 v = *reinterpret_cast<const float4*>(
        KV + ((size_t)(b * S_LEN + s0 + sl)) * DKV + 512 + g * 128 + d0 + dl4);
    tile[sl][dl4 + 0] = v.x; tile[sl][dl4 + 1] = v.y;
    tile[sl][dl4 + 2] = v.z; tile[sl][dl4 + 3] = v.w;
  }
  __syncthreads();
  {
    const int dl = t >> 3, sl4 = (t & 7) * 4;
    ushort4 o;
    o.x = f2bf(tile[sl4 + 0][dl]); o.y = f2bf(tile[sl4 + 1][dl]);
    o.z = f2bf(tile[sl4 + 2][dl]); o.w = f2bf(tile[sl4 + 3][dl]);
    *reinterpret_cast<ushort4*>(Vt + ((size_t)(bg * 128 + d0 + dl)) * S_LEN + s0 + sl4) = o;
  }
}

// ---------------- MFMA flash attention + gating ----------------
// grid (S/64, B*H); block 256 = 4 waves, wave w owns q rows [qt*64+w*16, +16)
__global__ __launch_bounds__(256) void attn(const u16* __restrict__ Qb,
                                            const u16* __restrict__ Kb,
                                            const u16* __restrict__ Vt,
                                            const float* __restrict__ QG,
                                            u16* __restrict__ ctxg) {
  __shared__ __align__(16) u16 Ks[32 * 128];   // [key][d]
  __shared__ __align__(16) u16 Vts[128 * 32];  // [d][key]
  __shared__ __align__(16) u16 Ps[4][16 * 32]; // per-wave P [q][key]
  const int tid = threadIdx.x, wv = tid >> 6, lane = tid & 63;
  const int qt = blockIdx.x, bh = blockIdx.y;
  const int b = bh >> 4, h = bh & 15, g = h >> 2, bg = b * 4 + g;
  const int frow = lane & 15, fq = (lane >> 4) * 8;
  const int srow = lane >> 2, skoff = (lane & 3) * 8;
  const u16* Qp = Qb + ((size_t)bh * S_LEN + qt * 64 + wv * 16) * 128;
  const u16* Kp = Kb + (size_t)bg * S_LEN * 128;
  const u16* Vp = Vt + (size_t)bg * 128 * S_LEN;

  bf16x8 aq[4];
#pragma unroll
  for (int c = 0; c < 4; ++c)
    aq[c] = *reinterpret_cast<const bf16x8*>(&Qp[(size_t)frow * 128 + c * 32 + fq]);

  floatx4 o[8] = {};
  float mrow[4] = {-__builtin_inff(), -__builtin_inff(), -__builtin_inff(), -__builtin_inff()};
  float lrow[4] = {0.f, 0.f, 0.f, 0.f};
  const float scale = 0.088388347648318447f;  // 128^-0.5
  const int nkt = qt * 2 + 2;

  for (int kt = 0; kt < nkt; ++kt) {
    const int k0 = kt * 32;
#pragma unroll
    for (int i = 0; i < 2; ++i) {
      const int off = (wv * 2 + i) * 512;       // contiguous K rows
      gload_lds16(Kp + (size_t)k0 * 128 + off + lane * 8, &Ks[off]);
      const int r0 = (wv * 2 + i) * 16;         // Vt rows (d)
      gload_lds16(Vp + (size_t)(r0 + srow) * S_LEN + k0 + skoff, &Vts[r0 * 32]);
    }
    __syncthreads();

    floatx4 sc0 = {}, sc1 = {};
#pragma unroll
    for (int c = 0; c < 4; ++c) {
      bf16x8 b0 = *reinterpret_cast<const bf16x8*>(&Ks[(size_t)frow * 128 + c * 32 + fq]);
      bf16x8 b1 = *reinterpret_cast<const bf16x8*>(&Ks[(size_t)(frow + 16) * 128 + c * 32 + fq]);
      sc0 = __builtin_amdgcn_mfma_f32_16x16x32_bf16(aq[c], b0, sc0, 0, 0, 0);
      sc1 = __builtin_amdgcn_mfma_f32_16x16x32_bf16(aq[c], b1, sc1, 0, 0, 0);
    }

    const int qrow0 = qt * 64 + wv * 16 + (lane >> 4) * 4;
    const int key0 = k0 + frow, key1 = key0 + 16;
    u16* Pw = Ps[wv];
#pragma unroll
    for (int r = 0; r < 4; ++r) {
      const int q = qrow0 + r;
      float x0 = (key0 <= q) ? sc0[r] * scale : -__builtin_inff();
      float x1 = (key1 <= q) ? sc1[r] * scale : -__builtin_inff();
      float mx = fmaxf(x0, x1);
#pragma unroll
      for (int mm = 8; mm >= 1; mm >>= 1) mx = fmaxf(mx, __shfl_xor(mx, mm));
      const float mnew = fmaxf(mrow[r], mx);
      const float alpha = __expf(mrow[r] - mnew);
      const float p0 = __expf(x0 - mnew), p1 = __expf(x1 - mnew);
      float ps = p0 + p1;
#pragma unroll
      for (int mm = 8; mm >= 1; mm >>= 1) ps += __shfl_xor(ps, mm);
      lrow[r] = lrow[r] * alpha + ps;
      mrow[r] = mnew;
#pragma unroll
      for (int dt = 0; dt < 8; ++dt) o[dt][r] *= alpha;
      const int prow = (lane >> 4) * 4 + r;
      Pw[prow * 32 + frow]      = f2bf(p0);
      Pw[prow * 32 + 16 + frow] = f2bf(p1);
    }
    // P: C-layout -> A-layout via LDS round trip (wave-private)
    bf16x8 pf = *reinterpret_cast<const bf16x8*>(&Pw[frow * 32 + fq]);
#pragma unroll
    for (int dt = 0; dt < 8; ++dt) {
      bf16x8 bv = *reinterpret_cast<const bf16x8*>(&Vts[(dt * 16 + frow) * 32 + fq]);
      o[dt] = __builtin_amdgcn_mfma_f32_16x16x32_bf16(pf, bv, o[dt], 0, 0, 0);
    }
    __syncthreads();
  }

  // epilogue: 1/l, sigmoid gate from QG, write bf16 ctx
#pragma unroll
  for (int r = 0; r < 4; ++r) {
    const int s = qt * 64 + wv * 16 + (lane >> 4) * 4 + r;
    const size_t grow = (size_t)b * S_LEN + s;
    const float inv = 1.0f / lrow[r];
#pragma unroll
    for (int dt = 0; dt < 8; ++dt) {
      const int d = dt * 16 + frow;
      const float gate = QG[grow * DQG + h * 256 + 128 + d];
      const float val = o[dt][r] * inv * (1.0f / (1.0f + __expf(-gate)));
      ctxg[grow * 2048 + h * 128 + d] = f2bf(val);
    }
  }
}

extern "C" void kernel_launch(void* const* d_in, const int* in_sizes, int n_in,
                              void* d_out, int out_size, void* d_ws, size_t ws_size,
                              hipStream_t stream) {
  const float* x    = (const float*)d_in[0];
  const float* Wq   = (const float*)d_in[1];
  const float* Wk   = (const float*)d_in[2];
  const float* Wv   = (const float*)d_in[3];
  const float* Wo   = (const float*)d_in[4];
  const float* qnw  = (const float*)d_in[5];
  const float* knw  = (const float*)d_in[6];
  const float* cosT = (const float*)d_in[7];
  const float* sinT = (const float*)d_in[8];
  // d_in[9] = mask (unused; causality computed analytically)

  char* p = (char*)d_ws;
  u16*   xb   = (u16*)p;  p += (size_t)NROWS * DIN * 2;       // x bf16
  u16*   WqT  = (u16*)p;  p += (size_t)DQG * DIN * 2;         // Wq^T
  u16*   WkvT = (u16*)p;  p += (size_t)DKV * DIN * 2;         // [Wk|Wv]^T
  u16*   WoT  = (u16*)p;  p += (size_t)2048 * 2048 * 2;       // Wo^T
  float* QGf  = (float*)p; p += (size_t)NROWS * DQG * 4;      // q|gate proj fp32
  float* KVf  = (float*)p; p += (size_t)NROWS * DKV * 4;      // k|v proj fp32
  u16*   Qbf  = (u16*)p;  p += (size_t)2 * 16 * S_LEN * 128 * 2;
  u16*   Kbf  = (u16*)p;  p += (size_t)2 * 4 * S_LEN * 128 * 2;
  u16*   Vtb  = (u16*)p;  p += (size_t)2 * 4 * S_LEN * 128 * 2;
  u16*   ctxg = (u16*)p;  p += (size_t)NROWS * 2048 * 2;

  cvt_f32_bf16<<<8192, 256, 0, stream>>>(x, xb, NROWS * DIN / 4);
  tcvt<<<dim3(128, 64), 256, 0, stream>>>(Wq, WqT, 2048, 4096, 2048);
  tcvt<<<dim3(16, 64), 256, 0, stream>>>(Wk, WkvT, 2048, 512, 2048);
  tcvt<<<dim3(16, 64), 256, 0, stream>>>(Wv, WkvT + (size_t)512 * 2048, 2048, 512, 2048);
  tcvt<<<dim3(64, 64), 256, 0, stream>>>(Wo, WoT, 2048, 2048, 2048);

  gemm_bt<<<dim3(32, 32), 256, 0, stream>>>(xb, WqT, QGf, NROWS, DQG, DIN);
  gemm_bt<<<dim3(8, 32), 256, 0, stream>>>(xb, WkvT, KVf, NROWS, DKV, DIN);

  qnorm_rope<<<16384, 256, 0, stream>>>(QGf, qnw, cosT, sinT, Qbf);
  knorm_rope<<<4096, 256, 0, stream>>>(KVf, knw, cosT, sinT, Kbf);
  vtrans<<<dim3(64, 4, 8), 256, 0, stream>>>(KVf, Vtb);

  attn<<<dim3(32, 32), 256, 0, stream>>>(Qbf, Kbf, Vtb, QGf, ctxg);

  gemm_bt<<<dim3(16, 32), 256, 0, stream>>>(ctxg, WoT, (float*)d_out, NROWS, 2048, 2048);
}

// Round 2
// 466.841 us; speedup vs baseline: 1.4192x; 1.4192x over previous
//
#include <hip/hip_runtime.h>

// Problem constants (B=2, S=2048, D_IN=2048, H=16, G=4, HD=128)
#define S_LEN 2048
#define NROWS 4096      // B*S
#define DIN   2048
#define DQG   4096      // 2*D_OUT
#define DKV   1024      // G*HD (K) + G*HD (V)

typedef __bf16 bf16x8 __attribute__((ext_vector_type(8)));
typedef float  floatx4 __attribute__((ext_vector_type(4)));
typedef unsigned short u16;

#define QK_SCALE 0.08838834764831845f   // 128^-0.5, folded into Q

__device__ __forceinline__ u16 f2bf(float f) {
  unsigned int u = __float_as_uint(f);
  u += 0x7fffu + ((u >> 16) & 1u);   // RNE
  return (u16)(u >> 16);
}

__device__ __forceinline__ void gload_lds16(const void* g, void* l) {
  __builtin_amdgcn_global_load_lds(
      (__attribute__((address_space(1))) void*)(void*)(g),
      (__attribute__((address_space(3))) void*)(l), 16, 0, 0);
}

// ---------------- elementwise fp32 -> bf16 ----------------
__global__ __launch_bounds__(256) void cvt_f32_bf16(const float* __restrict__ src,
                                                    u16* __restrict__ dst, int n4) {
  int i = blockIdx.x * 256 + threadIdx.x;
  if (i >= n4) return;
  float4 v = reinterpret_cast<const float4*>(src)[i];
  ushort4 o;
  o.x = f2bf(v.x); o.y = f2bf(v.y); o.z = f2bf(v.z); o.w = f2bf(v.w);
  reinterpret_cast<ushort4*>(dst)[i] = o;
}

// ---------------- transpose + convert: src[R][C] f32 -> dst[C][R] bf16 ----------------
__global__ __launch_bounds__(256) void tcvt(const float* __restrict__ src,
                                            u16* __restrict__ dst,
                                            int R, int C, int dld) {
  __shared__ float tile[32][33];
  const int c0 = blockIdx.x * 32, r0 = blockIdx.y * 32;
  const int t = threadIdx.x;
  {
    const int rl = t >> 3, cl4 = (t & 7) * 4;
    const float4 v = *reinterpret_cast<const float4*>(src + (size_t)(r0 + rl) * C + c0 + cl4);
    tile[rl][cl4 + 0] = v.x; tile[rl][cl4 + 1] = v.y;
    tile[rl][cl4 + 2] = v.z; tile[rl][cl4 + 3] = v.w;
  }
  __syncthreads();
  {
    const int cl = t >> 3, rl4 = (t & 7) * 4;
    ushort4 o;
    o.x = f2bf(tile[rl4 + 0][cl]); o.y = f2bf(tile[rl4 + 1][cl]);
    o.z = f2bf(tile[rl4 + 2][cl]); o.w = f2bf(tile[rl4 + 3][cl]);
    *reinterpret_cast<ushort4*>(dst + (size_t)(c0 + cl) * dld + r0 + rl4) = o;
  }
}

// ---------------- m97-style bf16 GEMM: C[M][N] = A[M][K] @ Bt[N][K]^T ----------------
__global__ __launch_bounds__(256) void gemm_bt(const u16* __restrict__ A,
                                               const u16* __restrict__ Bt,
                                               float* __restrict__ C,
                                               int M, int N, int K) {
  __shared__ __align__(16) u16 As[128 * 32];
  __shared__ __align__(16) u16 Bs[128 * 32];
  const int tid = threadIdx.x, wv = tid >> 6, lane = tid & 63;
  const int m0 = blockIdx.y * 128, n0 = blockIdx.x * 128;
  const int wm = (wv >> 1) * 64, wn = (wv & 1) * 64;
  const int frow = lane & 15, fk = (lane >> 4) * 8;
  const int srow = lane >> 2, skoff = (lane & 3) * 8;
  floatx4 acc[4][4] = {};
  for (int k0 = 0; k0 < K; k0 += 32) {
#pragma unroll
    for (int i = 0; i < 2; ++i) {
      const int rr = (wv * 2 + i) * 16;
      gload_lds16(A  + (size_t)(m0 + rr + srow) * K + k0 + skoff, &As[rr * 32]);
      gload_lds16(Bt + (size_t)(n0 + rr + srow) * K + k0 + skoff, &Bs[rr * 32]);
    }
    __syncthreads();
    bf16x8 af[4], bfr[4];
#pragma unroll
    for (int mi = 0; mi < 4; ++mi)
      af[mi] = *reinterpret_cast<const bf16x8*>(&As[(wm + mi * 16 + frow) * 32 + fk]);
#pragma unroll
    for (int ni = 0; ni < 4; ++ni)
      bfr[ni] = *reinterpret_cast<const bf16x8*>(&Bs[(wn + ni * 16 + frow) * 32 + fk]);
#pragma unroll
    for (int mi = 0; mi < 4; ++mi)
#pragma unroll
      for (int ni = 0; ni < 4; ++ni)
        acc[mi][ni] = __builtin_amdgcn_mfma_f32_16x16x32_bf16(af[mi], bfr[ni], acc[mi][ni], 0, 0, 0);
    __syncthreads();
  }
  const int crow = (lane >> 4) * 4, ccol = lane & 15;
#pragma unroll
  for (int mi = 0; mi < 4; ++mi)
#pragma unroll
    for (int ni = 0; ni < 4; ++ni) {
      float* cp = C + (size_t)(m0 + wm + mi * 16 + crow) * N + (n0 + wn + ni * 16 + ccol);
#pragma unroll
      for (int r = 0; r < 4; ++r) cp[(size_t)r * N] = acc[mi][ni][r];
    }
}

// ---------------- fused RMSNorm + RoPE for Q (scale folded in) ----------------
__global__ __launch_bounds__(256) void qnorm_rope(const float* __restrict__ QG,
                                                  const float* __restrict__ w,
                                                  const float* __restrict__ cosT,
                                                  const float* __restrict__ sinT,
                                                  u16* __restrict__ Qb) {
  const int wv = threadIdx.x >> 6, lane = threadIdx.x & 63;
  const int idx = blockIdx.x * 4 + wv;      // row*16 + h
  const int h = idx & 15, row = idx >> 4;   // row = b*S + s
  const int s = row & (S_LEN - 1), b = row >> 11;
  const float* base = QG + (size_t)row * DQG + h * 256;
  const float v0 = base[lane], v1 = base[lane + 64];
  float ss = v0 * v0 + v1 * v1;
#pragma unroll
  for (int m = 32; m >= 1; m >>= 1) ss += __shfl_xor(ss, m);
  const float rn = rsqrtf(ss * (1.0f / 128.0f) + 1e-6f) * QK_SCALE;
  const float n0 = v0 * rn * (1.0f + w[lane]);
  const float n1 = v1 * rn * (1.0f + w[lane + 64]);
  const float c0 = cosT[(size_t)s * 128 + lane], c1 = cosT[(size_t)s * 128 + lane + 64];
  const float sn0 = sinT[(size_t)s * 128 + lane], sn1 = sinT[(size_t)s * 128 + lane + 64];
  u16* qb = Qb + ((size_t)(b * 16 + h) * S_LEN + s) * 128;
  qb[lane]      = f2bf(n0 * c0 - n1 * sn0);
  qb[lane + 64] = f2bf(n1 * c1 + n0 * sn1);
}

// ---------------- fused RMSNorm + RoPE for K, XOR-swizzled layout ----------------
// row s stored as 16 chunks of 8 u16; chunk c stored at position c ^ (s&7)
__global__ __launch_bounds__(256) void knorm_rope(const float* __restrict__ KV,
                                                  const float* __restrict__ w,
                                                  const float* __restrict__ cosT,
                                                  const float* __restrict__ sinT,
                                                  u16* __restrict__ Kb) {
  const int wv = threadIdx.x >> 6, lane = threadIdx.x & 63;
  const int idx = blockIdx.x * 4 + wv;      // row*4 + g
  const int g = idx & 3, row = idx >> 2;
  const int s = row & (S_LEN - 1), b = row >> 11;
  const float* base = KV + (size_t)row * DKV + g * 128;
  const float v0 = base[lane], v1 = base[lane + 64];
  float ss = v0 * v0 + v1 * v1;
#pragma unroll
  for (int m = 32; m >= 1; m >>= 1) ss += __shfl_xor(ss, m);
  const float rn = rsqrtf(ss * (1.0f / 128.0f) + 1e-6f);
  const float n0 = v0 * rn * (1.0f + w[lane]);
  const float n1 = v1 * rn * (1.0f + w[lane + 64]);
  const float c0 = cosT[(size_t)s * 128 + lane], c1 = cosT[(size_t)s * 128 + lane + 64];
  const float sn0 = sinT[(size_t)s * 128 + lane], sn1 = sinT[(size_t)s * 128 + lane + 64];
  u16* kb = Kb + ((size_t)(b * 4 + g) * S_LEN + s) * 128;
  const int sw = s & 7;
  const int d0 = lane, d1 = lane + 64;
  const int p0 = (((d0 >> 3) ^ sw) << 3) | (d0 & 7);
  const int p1 = (((d1 >> 3) ^ sw) << 3) | (d1 & 7);
  kb[p0] = f2bf(n0 * c0 - n1 * sn0);
  kb[p1] = f2bf(n1 * c1 + n0 * sn1);
}

// ---------------- V transpose: KV fp32 cols 512.. -> Vt bf16 [bg][d][s], swizzled ----------------
// within each 64-key tile of row d: 8-key chunk c stored at c ^ (d&7)
__global__ __launch_bounds__(256) void vtrans(const float* __restrict__ KV,
                                              u16* __restrict__ Vt) {
  __shared__ float tile[32][33];
  const int bg = blockIdx.z;                 // b*4+g
  const int s0 = blockIdx.x * 32, d0 = blockIdx.y * 32;
  const int b = bg >> 2, g = bg & 3;
  const int t = threadIdx.x;
  {
    const int sl = t >> 3, dl4 = (t & 7) * 4;
    const float4 v = *reinterpret_cast<const float4*>(
        KV + ((size_t)(b * S_LEN + s0 + sl)) * DKV + 512 + g * 128 + d0 + dl4);
    tile[sl][dl4 + 0] = v.x; tile[sl][dl4 + 1] = v.y;
    tile[sl][dl4 + 2] = v.z; tile[sl][dl4 + 3] = v.w;
  }
  __syncthreads();
  {
    const int dl = t >> 3, sl4 = (t & 7) * 4;
    ushort4 o;
    o.x = f2bf(tile[sl4 + 0][dl]); o.y = f2bf(tile[sl4 + 1][dl]);
    o.z = f2bf(tile[sl4 + 2][dl]); o.w = f2bf(tile[sl4 + 3][dl]);
    const int d = d0 + dl, s = s0 + sl4;
    const size_t base = (size_t)(bg * 128 + d) * S_LEN + (s & ~63);
    const int pos = ((((s >> 3) & 7) ^ (d & 7)) << 3) | (s & 7);
    *reinterpret_cast<ushort4*>(Vt + base + pos) = o;
  }
}

// ---------------- MFMA flash attention + gating (no-max softmax, paired causal) ----------------
// grid (16, B*H); block = 4 waves. Block handles q-tiles ip and 31-ip (64 rows each),
// wave w owns 16 q rows. K-tile = 64 keys. Uniform 33 k-tiles per block.
__global__ __launch_bounds__(256) void attn(const u16* __restrict__ Qb,
                                            const u16* __restrict__ Kb,
                                            const u16* __restrict__ Vt,
                                            const float* __restrict__ QG,
                                            u16* __restrict__ ctxg) {
  __shared__ __align__(16) u16 Ks[64 * 128];   // [key][d], chunk-swizzled
  __shared__ __align__(16) u16 Vts[128 * 64];  // [d][key], chunk-swizzled
  __shared__ __align__(16) u16 Ps[4][16 * 68]; // per-wave P [q][key], stride 68
  const int tid = threadIdx.x, wv = tid >> 6, lane = tid & 63;
  const int ip = blockIdx.x, bh = blockIdx.y;
  const int b = bh >> 4, h = bh & 15, g = h >> 2, bg = b * 4 + g;
  const int f = lane & 15, quad = lane >> 4, fq = quad * 8;
  const int fsw = f & 7;
  const u16* Kp = Kb + (size_t)bg * S_LEN * 128;
  const u16* Vp = Vt + (size_t)bg * 128 * S_LEN;
  u16* Pw = Ps[wv];

  for (int pass = 0; pass < 2; ++pass) {
    const int qt = pass ? 31 - ip : ip;
    const u16* Qp = Qb + ((size_t)bh * S_LEN + qt * 64 + wv * 16) * 128;
    bf16x8 aq[4];
#pragma unroll
    for (int c = 0; c < 4; ++c)
      aq[c] = *reinterpret_cast<const bf16x8*>(&Qp[(size_t)f * 128 + c * 32 + fq]);

    floatx4 o[8] = {};
    float lsum[4] = {0.f, 0.f, 0.f, 0.f};
    const int nkt = qt + 1;

    for (int kt = 0; kt < nkt; ++kt) {
      const int k0 = kt * 64;
      // stage K tile: 64 rows x 256B, contiguous (swizzle baked into global layout)
#pragma unroll
      for (int i = 0; i < 4; ++i) {
        const int j = wv * 4 + i;
        gload_lds16(Kp + (size_t)k0 * 128 + j * 512 + lane * 8, &Ks[j * 512]);
      }
      // stage V tile: 128 rows x 128B (8 rows per gload)
#pragma unroll
      for (int i = 0; i < 4; ++i) {
        const int r0 = (wv * 4 + i) * 8;
        gload_lds16(Vp + (size_t)(r0 + (lane >> 3)) * S_LEN + k0 + (lane & 7) * 8,
                    &Vts[r0 * 64]);
      }
      __syncthreads();

      // QK^T: 16 q rows x 64 keys
      floatx4 sc[4] = {};
#pragma unroll
      for (int c = 0; c < 4; ++c) {
#pragma unroll
        for (int n = 0; n < 4; ++n) {
          bf16x8 bk = *reinterpret_cast<const bf16x8*>(
              &Ks[(n * 16 + f) * 128 + (((4 * c + quad) ^ fsw) << 3)]);
          sc[n] = __builtin_amdgcn_mfma_f32_16x16x32_bf16(aq[c], bk, sc[n], 0, 0, 0);
        }
      }

      // softmax without running max (scores bounded by sqrt(128))
      const int qrow0 = qt * 64 + wv * 16 + quad * 4;
#pragma unroll
      for (int n = 0; n < 4; ++n) {
        const int key = k0 + n * 16 + f;
#pragma unroll
        for (int r = 0; r < 4; ++r) {
          const float p = (key <= qrow0 + r) ? __expf(sc[n][r]) : 0.f;
          lsum[r] += p;
          Pw[(quad * 4 + r) * 68 + n * 16 + f] = f2bf(p);
        }
      }

      // P @ V (P is wave-private; compiler orders LDS write->read)
#pragma unroll
      for (int kf = 0; kf < 2; ++kf) {
        bf16x8 pf = *reinterpret_cast<const bf16x8*>(&Pw[f * 68 + kf * 32 + fq]);
#pragma unroll
        for (int dt = 0; dt < 8; ++dt) {
          bf16x8 bv = *reinterpret_cast<const bf16x8*>(
              &Vts[(dt * 16 + f) * 64 + (((4 * kf + quad) ^ fsw) << 3)]);
          o[dt] = __builtin_amdgcn_mfma_f32_16x16x32_bf16(pf, bv, o[dt], 0, 0, 0);
        }
      }
      __syncthreads();
    }

    // row sums: reduce lane-partials across the 16 f-lanes of each quad
#pragma unroll
    for (int r = 0; r < 4; ++r) {
#pragma unroll
      for (int mm = 8; mm >= 1; mm >>= 1) lsum[r] += __shfl_xor(lsum[r], mm);
    }

    // epilogue: 1/l, sigmoid gate, bf16 ctx write
#pragma unroll
    for (int r = 0; r < 4; ++r) {
      const int s = qt * 64 + wv * 16 + quad * 4 + r;
      const size_t grow = (size_t)b * S_LEN + s;
      const float inv = 1.0f / lsum[r];
#pragma unroll
      for (int dt = 0; dt < 8; ++dt) {
        const int d = dt * 16 + f;
        const float gate = QG[grow * DQG + h * 256 + 128 + d];
        const float val = o[dt][r] * inv * (1.0f / (1.0f + __expf(-gate)));
        ctxg[grow * 2048 + h * 128 + d] = f2bf(val);
      }
    }
  }
}

extern "C" void kernel_launch(void* const* d_in, const int* in_sizes, int n_in,
                              void* d_out, int out_size, void* d_ws, size_t ws_size,
                              hipStream_t stream) {
  const float* x    = (const float*)d_in[0];
  const float* Wq   = (const float*)d_in[1];
  const float* Wk   = (const float*)d_in[2];
  const float* Wv   = (const float*)d_in[3];
  const float* Wo   = (const float*)d_in[4];
  const float* qnw  = (const float*)d_in[5];
  const float* knw  = (const float*)d_in[6];
  const float* cosT = (const float*)d_in[7];
  const float* sinT = (const float*)d_in[8];
  // d_in[9] = mask (unused; causality computed analytically)

  char* p = (char*)d_ws;
  u16*   xb   = (u16*)p;  p += (size_t)NROWS * DIN * 2;       // x bf16
  u16*   WqT  = (u16*)p;  p += (size_t)DQG * DIN * 2;         // Wq^T
  u16*   WkvT = (u16*)p;  p += (size_t)DKV * DIN * 2;         // [Wk|Wv]^T
  u16*   WoT  = (u16*)p;  p += (size_t)2048 * 2048 * 2;       // Wo^T
  float* QGf  = (float*)p; p += (size_t)NROWS * DQG * 4;      // q|gate proj fp32
  float* KVf  = (float*)p; p += (size_t)NROWS * DKV * 4;      // k|v proj fp32
  u16*   Qbf  = (u16*)p;  p += (size_t)2 * 16 * S_LEN * 128 * 2;
  u16*   Kbf  = (u16*)p;  p += (size_t)2 * 4 * S_LEN * 128 * 2;
  u16*   Vtb  = (u16*)p;  p += (size_t)2 * 4 * S_LEN * 128 * 2;
  u16*   ctxg = (u16*)p;  p += (size_t)NROWS * 2048 * 2;

  cvt_f32_bf16<<<8192, 256, 0, stream>>>(x, xb, NROWS * DIN / 4);
  tcvt<<<dim3(128, 64), 256, 0, stream>>>(Wq, WqT, 2048, 4096, 2048);
  tcvt<<<dim3(16, 64), 256, 0, stream>>>(Wk, WkvT, 2048, 512, 2048);
  tcvt<<<dim3(16, 64), 256, 0, stream>>>(Wv, WkvT + (size_t)512 * 2048, 2048, 512, 2048);
  tcvt<<<dim3(64, 64), 256, 0, stream>>>(Wo, WoT, 2048, 2048, 2048);

  gemm_bt<<<dim3(32, 32), 256, 0, stream>>>(xb, WqT, QGf, NROWS, DQG, DIN);
  gemm_bt<<<dim3(8, 32), 256, 0, stream>>>(xb, WkvT, KVf, NROWS, DKV, DIN);

  qnorm_rope<<<16384, 256, 0, stream>>>(QGf, qnw, cosT, sinT, Qbf);
  knorm_rope<<<4096, 256, 0, stream>>>(KVf, knw, cosT, sinT, Kbf);
  vtrans<<<dim3(64, 4, 8), 256, 0, stream>>>(KVf, Vtb);

  attn<<<dim3(16, 32), 256, 0, stream>>>(Qbf, Kbf, Vtb, QGf, ctxg);

  gemm_bt<<<dim3(16, 32), 256, 0, stream>>>(ctxg, WoT, (float*)d_out, NROWS, 2048, 2048);
}

// Round 3
// 395.247 us; speedup vs baseline: 1.6762x; 1.1811x over previous
//
#include <hip/hip_runtime.h>

// Problem constants (B=2, S=2048, D_IN=2048, H=16, G=4, HD=128)
#define S_LEN 2048
#define NROWS 4096      // B*S
#define DIN   2048
#define DQKV  5120      // 4096 (q|gate) + 512 K + 512 V
#define DQG   4096

typedef __bf16 bf16x8 __attribute__((ext_vector_type(8)));
typedef float  floatx4 __attribute__((ext_vector_type(4)));
typedef unsigned short u16;

#define QK_SCALE 0.08838834764831845f   // 128^-0.5, folded into Q

__device__ __forceinline__ u16 f2bf(float f) {
  unsigned int u = __float_as_uint(f);
  u += 0x7fffu + ((u >> 16) & 1u);   // RNE
  return (u16)(u >> 16);
}
__device__ __forceinline__ float bf2f(u16 v) {
  return __uint_as_float(((unsigned int)v) << 16);
}
// XOR-8 chunk swizzle within each 64-element column group, keyed by row&7.
// Applied to all bf16 GEMM-operand matrices (baked into global layout so the
// position-preserving global_load_lds DMA lands it pre-swizzled in LDS).
__device__ __forceinline__ int swz(int col, int row) {
  return (col & ~63) | ((((col >> 3) & 7) ^ (row & 7)) << 3) | (col & 7);
}

__device__ __forceinline__ void gload_lds16(const void* g, void* l) {
  __builtin_amdgcn_global_load_lds(
      (__attribute__((address_space(1))) void*)(void*)(g),
      (__attribute__((address_space(3))) void*)(l), 16, 0, 0);
}

// ---------------- x fp32 -> bf16, swizzled (C = 2048) ----------------
__global__ __launch_bounds__(256) void cvt_x(const float* __restrict__ src,
                                             u16* __restrict__ dst) {
  const int i = blockIdx.x * 256 + threadIdx.x;   // one float4 per thread
  const int row = i >> 9, col = (i & 511) << 2;   // 512 float4 per row
  const float4 v = reinterpret_cast<const float4*>(src)[i];
  ushort4 o;
  o.x = f2bf(v.x); o.y = f2bf(v.y); o.z = f2bf(v.z); o.w = f2bf(v.w);
  *reinterpret_cast<ushort4*>(dst + (size_t)row * DIN + swz(col, row)) = o;
}

// ---------------- transpose + convert + swizzle: src[R][C] f32 -> dst[C][R] bf16 ----------------
__global__ __launch_bounds__(256) void tcvt(const float* __restrict__ src,
                                            u16* __restrict__ dst,
                                            int R, int C, int dld) {
  __shared__ float tile[32][33];
  const int c0 = blockIdx.x * 32, r0 = blockIdx.y * 32;
  const int t = threadIdx.x;
  {
    const int rl = t >> 3, cl4 = (t & 7) * 4;
    const float4 v = *reinterpret_cast<const float4*>(src + (size_t)(r0 + rl) * C + c0 + cl4);
    tile[rl][cl4 + 0] = v.x; tile[rl][cl4 + 1] = v.y;
    tile[rl][cl4 + 2] = v.z; tile[rl][cl4 + 3] = v.w;
  }
  __syncthreads();
  {
    const int cl = t >> 3, rl4 = (t & 7) * 4;
    ushort4 o;
    o.x = f2bf(tile[rl4 + 0][cl]); o.y = f2bf(tile[rl4 + 1][cl]);
    o.z = f2bf(tile[rl4 + 2][cl]); o.w = f2bf(tile[rl4 + 3][cl]);
    const int rd = c0 + cl, cd = r0 + rl4;      // dst (row, col)
    *reinterpret_cast<ushort4*>(dst + (size_t)rd * dld + swz(cd, rd)) = o;
  }
}

// ---------------- bf16 GEMM, BK=64: C[M][N] = A[M][K] @ Bt[N][K]^T ----------------
// A, Bt stored with swz() layout. C plain (fp32 or bf16).
template <bool BF16_OUT>
__global__ __launch_bounds__(256) void gemm_bt(const u16* __restrict__ A,
                                               const u16* __restrict__ Bt,
                                               void* __restrict__ Cv,
                                               int M, int N, int K) {
  __shared__ __align__(16) u16 As[128 * 64];
  __shared__ __align__(16) u16 Bs[128 * 64];
  const int tid = threadIdx.x, wv = tid >> 6, lane = tid & 63;
  const int m0 = blockIdx.y * 128, n0 = blockIdx.x * 128;
  const int wm = (wv >> 1) * 64, wn = (wv & 1) * 64;
  const int frow = lane & 15, quad = lane >> 4, fsw = frow & 7;
  const int srow = lane >> 3, scol = (lane & 7) * 8;
  floatx4 acc[4][4] = {};
  for (int k0 = 0; k0 < K; k0 += 64) {
#pragma unroll
    for (int i = 0; i < 4; ++i) {
      const int rr = (wv * 4 + i) * 8;
      gload_lds16(A  + (size_t)(m0 + rr + srow) * K + k0 + scol, &As[rr * 64]);
      gload_lds16(Bt + (size_t)(n0 + rr + srow) * K + k0 + scol, &Bs[rr * 64]);
    }
    __syncthreads();
#pragma unroll
    for (int ks = 0; ks < 2; ++ks) {
      bf16x8 af[4], bfr[4];
#pragma unroll
      for (int mi = 0; mi < 4; ++mi)
        af[mi] = *reinterpret_cast<const bf16x8*>(
            &As[(wm + mi * 16 + frow) * 64 + (((ks * 4 + quad) ^ fsw) << 3)]);
#pragma unroll
      for (int ni = 0; ni < 4; ++ni)
        bfr[ni] = *reinterpret_cast<const bf16x8*>(
            &Bs[(wn + ni * 16 + frow) * 64 + (((ks * 4 + quad) ^ fsw) << 3)]);
#pragma unroll
      for (int mi = 0; mi < 4; ++mi)
#pragma unroll
        for (int ni = 0; ni < 4; ++ni)
          acc[mi][ni] = __builtin_amdgcn_mfma_f32_16x16x32_bf16(af[mi], bfr[ni], acc[mi][ni], 0, 0, 0);
    }
    __syncthreads();
  }
  const int crow = (lane >> 4) * 4, ccol = lane & 15;
#pragma unroll
  for (int mi = 0; mi < 4; ++mi)
#pragma unroll
    for (int ni = 0; ni < 4; ++ni) {
      const size_t base = (size_t)(m0 + wm + mi * 16 + crow) * N + (n0 + wn + ni * 16 + ccol);
      if constexpr (BF16_OUT) {
        u16* C = (u16*)Cv;
#pragma unroll
        for (int r = 0; r < 4; ++r) C[base + (size_t)r * N] = f2bf(acc[mi][ni][r]);
      } else {
        float* C = (float*)Cv;
#pragma unroll
        for (int r = 0; r < 4; ++r) C[base + (size_t)r * N] = acc[mi][ni][r];
      }
    }
}

// ---------------- fused RMSNorm + RoPE for Q (scale folded in), bf16 in ----------------
__global__ __launch_bounds__(256) void qnorm_rope(const u16* __restrict__ QKV,
                                                  const float* __restrict__ w,
                                                  const float* __restrict__ cosT,
                                                  const float* __restrict__ sinT,
                                                  u16* __restrict__ Qb) {
  const int wv = threadIdx.x >> 6, lane = threadIdx.x & 63;
  const int idx = blockIdx.x * 4 + wv;      // row*16 + h
  const int h = idx & 15, row = idx >> 4;   // row = b*S + s
  const int s = row & (S_LEN - 1), b = row >> 11;
  const u16* base = QKV + (size_t)row * DQKV + h * 256;
  const float v0 = bf2f(base[lane]), v1 = bf2f(base[lane + 64]);
  float ss = v0 * v0 + v1 * v1;
#pragma unroll
  for (int m = 32; m >= 1; m >>= 1) ss += __shfl_xor(ss, m);
  const float rn = rsqrtf(ss * (1.0f / 128.0f) + 1e-6f) * QK_SCALE;
  const float n0 = v0 * rn * (1.0f + w[lane]);
  const float n1 = v1 * rn * (1.0f + w[lane + 64]);
  const float c0 = cosT[(size_t)s * 128 + lane], c1 = cosT[(size_t)s * 128 + lane + 64];
  const float sn0 = sinT[(size_t)s * 128 + lane], sn1 = sinT[(size_t)s * 128 + lane + 64];
  u16* qb = Qb + ((size_t)(b * 16 + h) * S_LEN + s) * 128;
  qb[lane]      = f2bf(n0 * c0 - n1 * sn0);
  qb[lane + 64] = f2bf(n1 * c1 + n0 * sn1);
}

// ---------------- fused RMSNorm + RoPE for K, XOR-swizzled attn layout ----------------
__global__ __launch_bounds__(256) void knorm_rope(const u16* __restrict__ QKV,
                                                  const float* __restrict__ w,
                                                  const float* __restrict__ cosT,
                                                  const float* __restrict__ sinT,
                                                  u16* __restrict__ Kb) {
  const int wv = threadIdx.x >> 6, lane = threadIdx.x & 63;
  const int idx = blockIdx.x * 4 + wv;      // row*4 + g
  const int g = idx & 3, row = idx >> 2;
  const int s = row & (S_LEN - 1), b = row >> 11;
  const u16* base = QKV + (size_t)row * DQKV + DQG + g * 128;
  const float v0 = bf2f(base[lane]), v1 = bf2f(base[lane + 64]);
  float ss = v0 * v0 + v1 * v1;
#pragma unroll
  for (int m = 32; m >= 1; m >>= 1) ss += __shfl_xor(ss, m);
  const float rn = rsqrtf(ss * (1.0f / 128.0f) + 1e-6f);
  const float n0 = v0 * rn * (1.0f + w[lane]);
  const float n1 = v1 * rn * (1.0f + w[lane + 64]);
  const float c0 = cosT[(size_t)s * 128 + lane], c1 = cosT[(size_t)s * 128 + lane + 64];
  const float sn0 = sinT[(size_t)s * 128 + lane], sn1 = sinT[(size_t)s * 128 + lane + 64];
  u16* kb = Kb + ((size_t)(b * 4 + g) * S_LEN + s) * 128;
  const int sw = s & 7;
  const int d0 = lane, d1 = lane + 64;
  const int p0 = (((d0 >> 3) ^ sw) << 3) | (d0 & 7);
  const int p1 = (((d1 >> 3) ^ sw) << 3) | (d1 & 7);
  kb[p0] = f2bf(n0 * c0 - n1 * sn0);
  kb[p1] = f2bf(n1 * c1 + n0 * sn1);
}

// ---------------- V: QKV bf16 cols 4608.. -> Vt bf16 [bg][d][s], attn-swizzled ----------------
__global__ __launch_bounds__(256) void vtrans(const u16* __restrict__ QKV,
                                              u16* __restrict__ Vt) {
  __shared__ u16 tile[32][40];
  const int bg = blockIdx.z;                 // b*4+g
  const int s0 = blockIdx.x * 32, d0 = blockIdx.y * 32;
  const int b = bg >> 2, g = bg & 3;
  const int t = threadIdx.x;
  {
    const int sl = t >> 3, dl4 = (t & 7) * 4;
    const ushort4 v = *reinterpret_cast<const ushort4*>(
        QKV + (size_t)(b * S_LEN + s0 + sl) * DQKV + DQG + 512 + g * 128 + d0 + dl4);
    tile[sl][dl4 + 0] = v.x; tile[sl][dl4 + 1] = v.y;
    tile[sl][dl4 + 2] = v.z; tile[sl][dl4 + 3] = v.w;
  }
  __syncthreads();
  {
    const int dl = t >> 3, sl4 = (t & 7) * 4;
    ushort4 o;
    o.x = tile[sl4 + 0][dl]; o.y = tile[sl4 + 1][dl];
    o.z = tile[sl4 + 2][dl]; o.w = tile[sl4 + 3][dl];
    const int d = d0 + dl, s = s0 + sl4;
    const size_t base = (size_t)(bg * 128 + d) * S_LEN + (s & ~63);
    const int pos = ((((s >> 3) & 7) ^ (d & 7)) << 3) | (s & 7);
    *reinterpret_cast<ushort4*>(Vt + base + pos) = o;
  }
}

// ---------------- MFMA flash attention + gating (no-max softmax, paired causal) ----------------
__global__ __launch_bounds__(256) void attn(const u16* __restrict__ Qb,
                                            const u16* __restrict__ Kb,
                                            const u16* __restrict__ Vt,
                                            const u16* __restrict__ QKV,
                                            u16* __restrict__ ctxg) {
  __shared__ __align__(16) u16 Ks[64 * 128];   // [key][d], chunk-swizzled
  __shared__ __align__(16) u16 Vts[128 * 64];  // [d][key], chunk-swizzled
  __shared__ __align__(16) u16 Ps[4][16 * 68]; // per-wave P [q][key], stride 68
  const int tid = threadIdx.x, wv = tid >> 6, lane = tid & 63;
  const int ip = blockIdx.x, bh = blockIdx.y;
  const int b = bh >> 4, h = bh & 15, g = h >> 2, bg = b * 4 + g;
  const int f = lane & 15, quad = lane >> 4, fq = quad * 8;
  const int fsw = f & 7;
  const u16* Kp = Kb + (size_t)bg * S_LEN * 128;
  const u16* Vp = Vt + (size_t)bg * 128 * S_LEN;
  u16* Pw = Ps[wv];

  for (int pass = 0; pass < 2; ++pass) {
    const int qt = pass ? 31 - ip : ip;
    const u16* Qp = Qb + ((size_t)bh * S_LEN + qt * 64 + wv * 16) * 128;
    bf16x8 aq[4];
#pragma unroll
    for (int c = 0; c < 4; ++c)
      aq[c] = *reinterpret_cast<const bf16x8*>(&Qp[(size_t)f * 128 + c * 32 + fq]);

    floatx4 o[8] = {};
    float lsum[4] = {0.f, 0.f, 0.f, 0.f};
    const int nkt = qt + 1;

    for (int kt = 0; kt < nkt; ++kt) {
      const int k0 = kt * 64;
#pragma unroll
      for (int i = 0; i < 4; ++i) {
        const int j = wv * 4 + i;
        gload_lds16(Kp + (size_t)k0 * 128 + j * 512 + lane * 8, &Ks[j * 512]);
      }
#pragma unroll
      for (int i = 0; i < 4; ++i) {
        const int r0 = (wv * 4 + i) * 8;
        gload_lds16(Vp + (size_t)(r0 + (lane >> 3)) * S_LEN + k0 + (lane & 7) * 8,
                    &Vts[r0 * 64]);
      }
      __syncthreads();

      floatx4 sc[4] = {};
#pragma unroll
      for (int c = 0; c < 4; ++c) {
#pragma unroll
        for (int n = 0; n < 4; ++n) {
          bf16x8 bk = *reinterpret_cast<const bf16x8*>(
              &Ks[(n * 16 + f) * 128 + (((4 * c + quad) ^ fsw) << 3)]);
          sc[n] = __builtin_amdgcn_mfma_f32_16x16x32_bf16(aq[c], bk, sc[n], 0, 0, 0);
        }
      }

      const int qrow0 = qt * 64 + wv * 16 + quad * 4;
#pragma unroll
      for (int n = 0; n < 4; ++n) {
        const int key = k0 + n * 16 + f;
#pragma unroll
        for (int r = 0; r < 4; ++r) {
          const float p = (key <= qrow0 + r) ? __expf(sc[n][r]) : 0.f;
          lsum[r] += p;
          Pw[(quad * 4 + r) * 68 + n * 16 + f] = f2bf(p);
        }
      }

#pragma unroll
      for (int kf = 0; kf < 2; ++kf) {
        bf16x8 pf = *reinterpret_cast<const bf16x8*>(&Pw[f * 68 + kf * 32 + fq]);
#pragma unroll
        for (int dt = 0; dt < 8; ++dt) {
          bf16x8 bv = *reinterpret_cast<const bf16x8*>(
              &Vts[(dt * 16 + f) * 64 + (((4 * kf + quad) ^ fsw) << 3)]);
          o[dt] = __builtin_amdgcn_mfma_f32_16x16x32_bf16(pf, bv, o[dt], 0, 0, 0);
        }
      }
      __syncthreads();
    }

#pragma unroll
    for (int r = 0; r < 4; ++r) {
#pragma unroll
      for (int mm = 8; mm >= 1; mm >>= 1) lsum[r] += __shfl_xor(lsum[r], mm);
    }

    // epilogue: 1/l, sigmoid gate (bf16), swizzled bf16 ctx write
#pragma unroll
    for (int r = 0; r < 4; ++r) {
      const int s = qt * 64 + wv * 16 + quad * 4 + r;
      const size_t grow = (size_t)b * S_LEN + s;
      const float inv = 1.0f / lsum[r];
#pragma unroll
      for (int dt = 0; dt < 8; ++dt) {
        const int d = dt * 16 + f;
        const float gate = bf2f(QKV[grow * DQKV + h * 256 + 128 + d]);
        const float val = o[dt][r] * inv * (1.0f / (1.0f + __expf(-gate)));
        const int col = h * 128 + d;
        ctxg[grow * 2048 + swz(col, (int)grow)] = f2bf(val);
      }
    }
  }
}

extern "C" void kernel_launch(void* const* d_in, const int* in_sizes, int n_in,
                              void* d_out, int out_size, void* d_ws, size_t ws_size,
                              hipStream_t stream) {
  const float* x    = (const float*)d_in[0];
  const float* Wq   = (const float*)d_in[1];
  const float* Wk   = (const float*)d_in[2];
  const float* Wv   = (const float*)d_in[3];
  const float* Wo   = (const float*)d_in[4];
  const float* qnw  = (const float*)d_in[5];
  const float* knw  = (const float*)d_in[6];
  const float* cosT = (const float*)d_in[7];
  const float* sinT = (const float*)d_in[8];
  // d_in[9] = mask (unused; causality computed analytically)

  char* p = (char*)d_ws;
  u16*   xb    = (u16*)p;  p += (size_t)NROWS * DIN * 2;       // x bf16 (swizzled)
  u16*   WqkvT = (u16*)p;  p += (size_t)DQKV * DIN * 2;        // [Wq|Wk|Wv]^T (swizzled)
  u16*   WoT   = (u16*)p;  p += (size_t)2048 * 2048 * 2;       // Wo^T (swizzled)
  u16*   QKVb  = (u16*)p;  p += (size_t)NROWS * DQKV * 2;      // qkv proj bf16 (plain)
  u16*   Qbf   = (u16*)p;  p += (size_t)2 * 16 * S_LEN * 128 * 2;
  u16*   Kbf   = (u16*)p;  p += (size_t)2 * 4 * S_LEN * 128 * 2;
  u16*   Vtb   = (u16*)p;  p += (size_t)2 * 4 * S_LEN * 128 * 2;
  u16*   ctxg  = (u16*)p;  p += (size_t)NROWS * 2048 * 2;      // gated ctx (swizzled)

  cvt_x<<<8192, 256, 0, stream>>>(x, xb);
  tcvt<<<dim3(128, 64), 256, 0, stream>>>(Wq, WqkvT, 2048, 4096, 2048);
  tcvt<<<dim3(16, 64), 256, 0, stream>>>(Wk, WqkvT + (size_t)4096 * 2048, 2048, 512, 2048);
  tcvt<<<dim3(16, 64), 256, 0, stream>>>(Wv, WqkvT + (size_t)4608 * 2048, 2048, 512, 2048);
  tcvt<<<dim3(64, 64), 256, 0, stream>>>(Wo, WoT, 2048, 2048, 2048);

  gemm_bt<true><<<dim3(40, 32), 256, 0, stream>>>(xb, WqkvT, QKVb, NROWS, DQKV, DIN);

  qnorm_rope<<<16384, 256, 0, stream>>>(QKVb, qnw, cosT, sinT, Qbf);
  knorm_rope<<<4096, 256, 0, stream>>>(QKVb, knw, cosT, sinT, Kbf);
  vtrans<<<dim3(64, 4, 8), 256, 0, stream>>>(QKVb, Vtb);

  attn<<<dim3(16, 32), 256, 0, stream>>>(Qbf, Kbf, Vtb, QKVb, ctxg);

  gemm_bt<false><<<dim3(16, 32), 256, 0, stream>>>(ctxg, WoT, (float*)d_out, NROWS, 2048, 2048);
}